// Round 4
// baseline (2085.676 us; speedup 1.0000x reference)
//
#include <hip/hip_runtime.h>

// Attractor net (all I/O float32): c = x@Win^T + bin; a=0; 15x: a = tanh(a@Ws^T + b + c),
// Ws = 0.5(W+W^T); y = a@Wout^T + bout.  x (65536,256), N=512, C=256.
//
// Round-4: attack A-load latency (R3 showed ~2380 cyc/K-step vs ~130 cyc of issue work).
//  - Depth-6 rotating register prefetch of Ws A-fragments, K-loop fully unrolled ->
//    12 outstanding global loads per wave (fine-grained vmcnt, never drains to 0).
//  - c no longer held in 64 VGPRs: phase 1 stores c (biases folded) bf16-packed in
//    B-fragment layout into the block's own d_out region; each iteration re-reads it
//    (prefetched at K-steps 26..31) and adds it via 2 identity-A MFMA steps. The freed
//    registers pay for the prefetch pipeline. y overwrites the region only afterwards.
//  - Everything else (128 samples/block, 512 thr, XOR-swizzled a in LDS) as round 3.

using bf16x8 = __attribute__((ext_vector_type(8))) __bf16;
using f32x16 = __attribute__((ext_vector_type(16))) float;

union BQ {
  unsigned long long q[2];
  uint4 u4;
};

// round-to-nearest bf16 pack of two floats into one u32 (lo = a, hi = b)
__device__ __forceinline__ unsigned int pack2bf(float a, float b) {
  unsigned int ua = __builtin_bit_cast(unsigned int, a);
  unsigned int ub = __builtin_bit_cast(unsigned int, b);
  return ((ua + 0x8000u) >> 16) | ((ub + 0x8000u) & 0xffff0000u);
}

__device__ __forceinline__ unsigned short f2bf(float v) {
  unsigned int u = __builtin_bit_cast(unsigned int, v);
  return (unsigned short)((u + 0x7fffu + ((u >> 16) & 1u)) >> 16);  // RNE
}

__device__ __forceinline__ float fast_tanh(float x) {
  float e = __builtin_amdgcn_exp2f(x * 2.885390082f);
  float r = __builtin_amdgcn_rcpf(e + 1.0f);
  return __builtin_fmaf(-2.0f, r, 1.0f);
}

__device__ __forceinline__ f32x16 mfma32(uint4 a, uint4 b, f32x16 c) {
  return __builtin_amdgcn_mfma_f32_32x32x16_bf16(
      __builtin_bit_cast(bf16x8, a), __builtin_bit_cast(bf16x8, b), c, 0, 0, 0);
}

// ---------------- prep ----------------
// WsP = bf16 A-fragment layout of 0.5*(W + W^T); Win/Wout row-major f32->bf16.
__global__ void prep(const float* __restrict__ W,
                     const float* __restrict__ Win,
                     const float* __restrict__ Wout,
                     unsigned short* __restrict__ WsPo,
                     unsigned short* __restrict__ WinBf,
                     unsigned short* __restrict__ WoutBf) {
  int t = blockIdx.x * 256 + threadIdx.x;   // 0 .. 262143
  int e   = t & 511;
  int bid = t >> 9;
  int s  = bid >> 4;
  int mt = bid & 15;
  int L = e >> 3, j = e & 7;
  int m = mt * 32 + (L & 31);
  int k = s * 16 + (L >> 5) * 8 + j;
  WsPo[t] = f2bf(0.5f * (W[m * 512 + k] + W[k * 512 + m]));
  if (t < 131072) WinBf[t] = f2bf(Win[t]);
  else            WoutBf[t - 131072] = f2bf(Wout[t - 131072]);
}

// ---------------- main fused kernel ----------------
__global__ __launch_bounds__(512, 2) void attractor_kernel(
    const float* __restrict__ x,              // 65536 x 256 f32
    const unsigned short* __restrict__ WinBf, // 512 x 256 bf16
    const float* __restrict__ binf,           // 512 f32
    const float* __restrict__ brecf,          // 512 f32
    const unsigned short* __restrict__ WoutBf,// 256 x 512 bf16
    const float* __restrict__ boutf,          // 256 f32
    const uint4* __restrict__ WsP,            // packed 512 KB bf16
    float* y)                                 // 65536 x 256 f32 (also c staging!)
{
  __shared__ uint4 smem4[8320];               // 133,120 B (a: 128KB; y-stage: 128x65 uint4)
  unsigned long long* a_sh = (unsigned long long*)smem4;

  const int tid  = threadIdx.x;
  const int lane = tid & 63;
  const int w    = tid >> 6;    // wave 0..7
  const int il   = lane & 31;   // row-within-32-tile
  const int g    = lane >> 5;   // k-group (0/1)
  const int m15  = il & 15;     // LDS swizzle mask
  const int blk  = blockIdx.x;

  const float4* __restrict__ xf4  = (const float4*)x;       // row = 64 float4
  const uint4* __restrict__ Win4  = (const uint4*)WinBf;    // row = 32 uint4
  const uint4* __restrict__ Wout4 = (const uint4*)WoutBf;   // row = 64 uint4
  uint4* y4 = (uint4*)y;                                    // row = 64 uint4
  // block-private c staging region (exactly the block's y slice, used before y is written)
  char* cbase = (char*)y + (size_t)blk * 131072 + w * 16384;

  // identity A-operand fragments: A[m][k] = (m == k + 16*sg)
  uint4 idA[2];
  {
    unsigned int wd[2][4];
    #pragma unroll
    for (int sg = 0; sg < 2; ++sg)
      #pragma unroll
      for (int jj = 0; jj < 4; ++jj) {
        unsigned int lo = (il == g * 8 + 2 * jj + 0 + 16 * sg) ? 0x3F80u : 0u;
        unsigned int hi = (il == g * 8 + 2 * jj + 1 + 16 * sg) ? 0x3F80u : 0u;
        wd[sg][jj] = lo | (hi << 16);
      }
    idA[0] = uint4{wd[0][0], wd[0][1], wd[0][2], wd[0][3]};
    idA[1] = uint4{wd[1][0], wd[1][1], wd[1][2], wd[1][3]};
  }

  f32x16 acc[2][4];             // [mt][nt], 128 VGPRs

  // ---------- Phase 1: in_proj  c^T = Win @ x^T  (K = 256 -> 16 steps) ----------
  #pragma unroll
  for (int mt = 0; mt < 2; ++mt)
    #pragma unroll
    for (int nt = 0; nt < 4; ++nt)
      #pragma unroll
      for (int r = 0; r < 16; ++r) acc[mt][nt][r] = 0.0f;

  #pragma unroll 2
  for (int s = 0; s < 16; ++s) {
    uint4 A[2], B[4];
    #pragma unroll
    for (int mt = 0; mt < 2; ++mt) {
      int m = w * 64 + mt * 32 + il;           // feature row of Win
      A[mt] = Win4[m * 32 + 2 * s + g];
    }
    #pragma unroll
    for (int nt = 0; nt < 4; ++nt) {
      int i = blk * 128 + nt * 32 + il;        // sample row of x
      float4 f0 = xf4[i * 64 + 4 * s + 2 * g + 0];
      float4 f1 = xf4[i * 64 + 4 * s + 2 * g + 1];
      B[nt].x = pack2bf(f0.x, f0.y);
      B[nt].y = pack2bf(f0.z, f0.w);
      B[nt].z = pack2bf(f1.x, f1.y);
      B[nt].w = pack2bf(f1.z, f1.w);
    }
    #pragma unroll
    for (int mt = 0; mt < 2; ++mt)
      #pragma unroll
      for (int nt = 0; nt < 4; ++nt)
        acc[mt][nt] = mfma32(A[mt], B[nt], acc[mt][nt]);
  }

  // epilogue: fold biases into c
  #pragma unroll
  for (int mt = 0; mt < 2; ++mt) {
    #pragma unroll
    for (int p = 0; p < 4; ++p) {
      const int n0 = w * 64 + mt * 32 + 8 * p + 4 * g;
      float b0 = binf[n0 + 0] + brecf[n0 + 0];
      float b1 = binf[n0 + 1] + brecf[n0 + 1];
      float b2 = binf[n0 + 2] + brecf[n0 + 2];
      float b3 = binf[n0 + 3] + brecf[n0 + 3];
      #pragma unroll
      for (int nt = 0; nt < 4; ++nt) {
        acc[mt][nt][4 * p + 0] += b0;
        acc[mt][nt][4 * p + 1] += b1;
        acc[mt][nt][4 * p + 2] += b2;
        acc[mt][nt][4 * p + 3] += b3;
      }
    }
  }

  // write c as bf16 B-operand fragments into the block's d_out region.
  // fragment f = mt*8 + sg*4 + nt (1 KB each); element (k = 8h+4g+q, i = il)
  // -> byte (32h+il)*16 + 8g, value acc[mt][nt][4*(2*sg+h)+q]. 512-B coalesced waves.
  #pragma unroll
  for (int mt = 0; mt < 2; ++mt)
    #pragma unroll
    for (int sg = 0; sg < 2; ++sg)
      #pragma unroll
      for (int h = 0; h < 2; ++h)
        #pragma unroll
        for (int nt = 0; nt < 4; ++nt) {
          const int r0 = 4 * (2 * sg + h);
          uint2 v;
          v.x = pack2bf(acc[mt][nt][r0 + 0], acc[mt][nt][r0 + 1]);
          v.y = pack2bf(acc[mt][nt][r0 + 2], acc[mt][nt][r0 + 3]);
          *(uint2*)(cbase + (mt * 8 + sg * 4 + nt) * 1024 + (32 * h + il) * 16 + 8 * g) = v;
        }

  // tanh + swizzled bf16 store of a into LDS
  auto tanhStore = [&]() {
    #pragma unroll
    for (int mt = 0; mt < 2; ++mt)
      #pragma unroll
      for (int nt = 0; nt < 4; ++nt) {
        const int irow = nt * 32 + il;
        #pragma unroll
        for (int p = 0; p < 4; ++p) {
          float t0 = fast_tanh(acc[mt][nt][4 * p + 0]);
          float t1 = fast_tanh(acc[mt][nt][4 * p + 1]);
          float t2 = fast_tanh(acc[mt][nt][4 * p + 2]);
          float t3 = fast_tanh(acc[mt][nt][4 * p + 3]);
          unsigned long long qv =
              (unsigned long long)pack2bf(t0, t1) |
              ((unsigned long long)pack2bf(t2, t3) << 32);
          const int u = w * 16 + mt * 8 + 2 * p + g;   // 8B unit within 128-unit row
          a_sh[irow * 128 + (u ^ m15)] = qv;
        }
      }
  };
  tanhStore();
  __syncthreads();

  // ---------- Phase 2: 14 iterations  z^T = Ws @ a^T + c  (K = 512 -> 32 steps) ----------
  const uint4* pA = WsP + (w * 2) * 64 + lane;   // + s*1024 + mt*64

  uint4 Abuf[6][2];   // depth-6 rotating prefetch pipeline
  #pragma unroll
  for (int s0 = 0; s0 < 6; ++s0)
    #pragma unroll
    for (int mt = 0; mt < 2; ++mt) Abuf[s0][mt] = pA[s0 * 1024 + mt * 64];

  #pragma unroll 1
  for (int it = 0; it < 14; ++it) {
    #pragma unroll
    for (int mt = 0; mt < 2; ++mt)
      #pragma unroll
      for (int nt = 0; nt < 4; ++nt)
        #pragma unroll
        for (int r = 0; r < 16; ++r) acc[mt][nt][r] = 0.0f;

    uint4 cB[16];

    #pragma unroll
    for (int s = 0; s < 32; ++s) {
      const int u0 = 4 * s + 2 * g;
      BQ B[4];
      #pragma unroll
      for (int nt = 0; nt < 4; ++nt) {
        const int base = (nt * 32 + il) * 128;
        B[nt].q[0] = a_sh[base + ((u0 + 0) ^ m15)];
        B[nt].q[1] = a_sh[base + ((u0 + 1) ^ m15)];
      }
      #pragma unroll
      for (int mt = 0; mt < 2; ++mt)
        #pragma unroll
        for (int nt = 0; nt < 4; ++nt)
          acc[mt][nt] = mfma32(Abuf[s % 6][mt], B[nt].u4, acc[mt][nt]);
      if (s + 6 < 32) {
        #pragma unroll
        for (int mt = 0; mt < 2; ++mt)
          Abuf[s % 6][mt] = pA[(s + 6) * 1024 + mt * 64];
      }
      if (s >= 26) {   // prefetch c fragments, 3 per step (16 total)
        #pragma unroll
        for (int t = 0; t < 3; ++t) {
          const int f = (s - 26) * 3 + t;
          if (f < 16)
            cB[f] = *(const uint4*)(cbase + f * 1024 + lane * 16);
        }
      }
    }

    // add c via identity-A MFMA steps
    #pragma unroll
    for (int f = 0; f < 16; ++f) {
      const int mt = f >> 3, sg = (f >> 2) & 1, nt = f & 3;
      acc[mt][nt] = mfma32(idA[sg], cB[f], acc[mt][nt]);
    }

    // preload next iteration's first 6 A-steps (hidden by tanh + barriers)
    if (it != 13) {
      #pragma unroll
      for (int s0 = 0; s0 < 6; ++s0)
        #pragma unroll
        for (int mt = 0; mt < 2; ++mt) Abuf[s0][mt] = pA[s0 * 1024 + mt * 64];
    }

    __syncthreads();   // all reads of old a done
    tanhStore();       // overwrite a in place
    __syncthreads();   // new a visible to all waves
  }

  // ---------- Phase 3: out_proj  y^T = Wout @ a^T (wave w -> channels [w*32, w*32+32)) ----------
  f32x16 o[4];
  #pragma unroll
  for (int nt = 0; nt < 4; ++nt)
    #pragma unroll
    for (int r = 0; r < 16; ++r) o[nt][r] = 0.0f;

  #pragma unroll 2
  for (int s = 0; s < 32; ++s) {
    const int m = w * 32 + il;                  // output-channel row of Wout
    uint4 A = Wout4[m * 64 + 2 * s + g];
    const int u0 = 4 * s + 2 * g;
    BQ B[4];
    #pragma unroll
    for (int nt = 0; nt < 4; ++nt) {
      const int base = (nt * 32 + il) * 128;
      B[nt].q[0] = a_sh[base + ((u0 + 0) ^ m15)];
      B[nt].q[1] = a_sh[base + ((u0 + 1) ^ m15)];
    }
    #pragma unroll
    for (int nt = 0; nt < 4; ++nt)
      o[nt] = mfma32(A, B[nt].u4, o[nt]);
  }
  __syncthreads();   // done reading a; reuse LDS as y staging

  // epilogue: +bout, stage f32 rows into LDS (stride-65 uint4 rows)
  uint4* yst4 = smem4;
  #pragma unroll
  for (int p = 0; p < 4; ++p) {
    const int c0 = w * 32 + 8 * p + 4 * g;
    float b0 = boutf[c0 + 0];
    float b1 = boutf[c0 + 1];
    float b2 = boutf[c0 + 2];
    float b3 = boutf[c0 + 3];
    #pragma unroll
    for (int nt = 0; nt < 4; ++nt) {
      const int irow = nt * 32 + il;
      float4 r;
      r.x = o[nt][4 * p + 0] + b0;
      r.y = o[nt][4 * p + 1] + b1;
      r.z = o[nt][4 * p + 2] + b2;
      r.w = o[nt][4 * p + 3] + b3;
      yst4[irow * 65 + (c0 >> 2)] = __builtin_bit_cast(uint4, r);
    }
  }
  __syncthreads();

  // coalesced f32 store: 8192 uint4 per block, 16 passes x 512 threads
  #pragma unroll
  for (int p = 0; p < 16; ++p) {
    int idx = p * 512 + tid;
    int row = idx >> 6;
    int col = idx & 63;
    y4[(blk * 128 + row) * 64 + col] = yst4[row * 65 + col];
  }
}

extern "C" void kernel_launch(void* const* d_in, const int* in_sizes, int n_in,
                              void* d_out, int out_size, void* d_ws, size_t ws_size,
                              hipStream_t stream) {
  const float* x    = (const float*)d_in[0];
  const float* Win  = (const float*)d_in[1];
  const float* bin  = (const float*)d_in[2];
  const float* W    = (const float*)d_in[3];
  const float* brec = (const float*)d_in[4];
  const float* Wout = (const float*)d_in[5];
  const float* bout = (const float*)d_in[6];

  unsigned short* wsu    = (unsigned short*)d_ws;
  unsigned short* WsP    = wsu;            // 262144 bf16 = 512 KB
  unsigned short* WinBf  = wsu + 262144;   // 131072 bf16 = 256 KB
  unsigned short* WoutBf = wsu + 393216;   // 131072 bf16 = 256 KB

  prep<<<1024, 256, 0, stream>>>(W, Win, Wout, WsP, WinBf, WoutBf);
  attractor_kernel<<<512, 512, 0, stream>>>(x, WinBf, bin, brec, WoutBf, bout,
                                            (const uint4*)WsP, (float*)d_out);
}

// Round 5
// 1445.311 us; speedup vs baseline: 1.4431x; 1.4431x over previous
//
#include <hip/hip_runtime.h>

// Attractor net (all I/O float32): c = x@Win^T + bin; a=0; 15x: a = tanh(a@Ws^T + b + c),
// Ws = 0.5(W+W^T); y = a@Wout^T + bout.  x (65536,256), N=512, C=256.
//
// Round-5 = Round-3 structure (c in regs, 128 samples/block, 512 thr, 1 block/CU) plus:
//  - LDS swizzle mask il&14 (even bits only): B-pairs stay 16-B aligned & ordered ->
//    4x ds_read_b128 per K-step (was 8x ds_read_b64) and per-step B addressing is
//    one v_xor + one v_add (pairByte = (32*ss)^vGMb, nt via offset immediates).
//  - Per-block K-rotation ss=(s+sOff)&31: de-lockstep the Ws read stream across blocks
//    so L2 serves different lines to different CUs each instant (sum order-independent).
//  - Distance-2 register prefetch of Ws A-fragments, fully unrolled 32-step K-loop.
// R4's c-in-global reverted (it evicted Ws from the 4MB per-XCD L2 -> HBM-bound).

using bf16x8 = __attribute__((ext_vector_type(8))) __bf16;
using f32x16 = __attribute__((ext_vector_type(16))) float;

// round-to-nearest bf16 pack of two floats into one u32 (lo = a, hi = b)
__device__ __forceinline__ unsigned int pack2bf(float a, float b) {
  unsigned int ua = __builtin_bit_cast(unsigned int, a);
  unsigned int ub = __builtin_bit_cast(unsigned int, b);
  return ((ua + 0x8000u) >> 16) | ((ub + 0x8000u) & 0xffff0000u);
}

__device__ __forceinline__ unsigned short f2bf(float v) {
  unsigned int u = __builtin_bit_cast(unsigned int, v);
  return (unsigned short)((u + 0x7fffu + ((u >> 16) & 1u)) >> 16);  // RNE
}

__device__ __forceinline__ float fast_tanh(float x) {
  float e = __builtin_amdgcn_exp2f(x * 2.885390082f);
  float r = __builtin_amdgcn_rcpf(e + 1.0f);
  return __builtin_fmaf(-2.0f, r, 1.0f);
}

__device__ __forceinline__ f32x16 mfma32(uint4 a, uint4 b, f32x16 c) {
  return __builtin_amdgcn_mfma_f32_32x32x16_bf16(
      __builtin_bit_cast(bf16x8, a), __builtin_bit_cast(bf16x8, b), c, 0, 0, 0);
}

// ---------------- prep ----------------
// WsP = bf16 A-fragment layout of 0.5*(W + W^T); Win/Wout row-major f32->bf16.
// Fragment block (s, mtG) is 1KB: lane L holds Ws[m = mtG*32 + (L&31)][k = s*16 + (L>>5)*8 + j]
// at element offset ((s*16+mtG)*64 + L)*8 + j.
__global__ void prep(const float* __restrict__ W,
                     const float* __restrict__ Win,
                     const float* __restrict__ Wout,
                     unsigned short* __restrict__ WsPo,
                     unsigned short* __restrict__ WinBf,
                     unsigned short* __restrict__ WoutBf) {
  int t = blockIdx.x * 256 + threadIdx.x;   // 0 .. 262143
  int e   = t & 511;
  int bid = t >> 9;
  int s  = bid >> 4;
  int mt = bid & 15;
  int L = e >> 3, j = e & 7;
  int m = mt * 32 + (L & 31);
  int k = s * 16 + (L >> 5) * 8 + j;
  WsPo[t] = f2bf(0.5f * (W[m * 512 + k] + W[k * 512 + m]));
  if (t < 131072) WinBf[t] = f2bf(Win[t]);
  else            WoutBf[t - 131072] = f2bf(Wout[t - 131072]);
}

// ---------------- main fused kernel ----------------
__global__ __launch_bounds__(512, 2) void attractor_kernel(
    const float* __restrict__ x,              // 65536 x 256 f32
    const unsigned short* __restrict__ WinBf, // 512 x 256 bf16
    const float* __restrict__ binf,           // 512 f32
    const float* __restrict__ brecf,          // 512 f32
    const unsigned short* __restrict__ WoutBf,// 256 x 512 bf16
    const float* __restrict__ boutf,          // 256 f32
    const uint4* __restrict__ WsP,            // packed 512 KB bf16
    float* __restrict__ y)                    // 65536 x 256 f32
{
  __shared__ uint4 smem4[8320];               // 133,120 B (a: 128KB; y-stage: 128x65 uint4)
  char* aC = (char*)smem4;

  const int tid  = threadIdx.x;
  const int lane = tid & 63;
  const int w    = tid >> 6;    // wave 0..7
  const int il   = lane & 31;   // row-within-32-tile
  const int g    = lane >> 5;   // k-group (0/1)
  const int m14  = il & 14;     // LDS swizzle mask (even bits -> 16B pairs stay ordered)
  const int blk  = blockIdx.x;
  const int sOff = (blk >> 3) & 31;             // per-block K rotation
  const int vGMb = ((2 * g) ^ m14) * 8;         // lane part of B pair byte offset
  const int rdRow = il * 1024;                  // B read row base (nt via +32768)
  const int laneW = w * 128 + g * 8 + m14 * 8;  // lane part of a-store byte offset

  const float4* __restrict__ xf4  = (const float4*)x;       // row = 64 float4
  const uint4* __restrict__ Win4  = (const uint4*)WinBf;    // row = 32 uint4
  const uint4* __restrict__ Wout4 = (const uint4*)WoutBf;   // row = 64 uint4
  uint4* __restrict__ y4 = (uint4*)y;                       // row = 64 uint4

  f32x16 acc[2][4];             // [mt][nt], 128 regs (AGPR)
  unsigned int c_pk[2][4][8];   // 64 VGPRs

  // ---------- Phase 1: in_proj  c^T = Win @ x^T  (K = 256 -> 16 steps) ----------
  #pragma unroll
  for (int mt = 0; mt < 2; ++mt)
    #pragma unroll
    for (int nt = 0; nt < 4; ++nt)
      #pragma unroll
      for (int r = 0; r < 16; ++r) acc[mt][nt][r] = 0.0f;

  #pragma unroll 2
  for (int s = 0; s < 16; ++s) {
    uint4 A[2], B[4];
    #pragma unroll
    for (int mt = 0; mt < 2; ++mt) {
      int m = w * 64 + mt * 32 + il;           // feature row of Win
      A[mt] = Win4[m * 32 + 2 * s + g];
    }
    #pragma unroll
    for (int nt = 0; nt < 4; ++nt) {
      int i = blk * 128 + nt * 32 + il;        // sample row of x
      float4 f0 = xf4[i * 64 + 4 * s + 2 * g + 0];
      float4 f1 = xf4[i * 64 + 4 * s + 2 * g + 1];
      B[nt].x = pack2bf(f0.x, f0.y);
      B[nt].y = pack2bf(f0.z, f0.w);
      B[nt].z = pack2bf(f1.x, f1.y);
      B[nt].w = pack2bf(f1.z, f1.w);
    }
    #pragma unroll
    for (int mt = 0; mt < 2; ++mt)
      #pragma unroll
      for (int nt = 0; nt < 4; ++nt)
        acc[mt][nt] = mfma32(A[mt], B[nt], acc[mt][nt]);
  }

  // epilogue: fold biases into c, stash packed c
  #pragma unroll
  for (int mt = 0; mt < 2; ++mt) {
    #pragma unroll
    for (int p = 0; p < 4; ++p) {
      const int n0 = w * 64 + mt * 32 + 8 * p + 4 * g;
      float b0 = binf[n0 + 0] + brecf[n0 + 0];
      float b1 = binf[n0 + 1] + brecf[n0 + 1];
      float b2 = binf[n0 + 2] + brecf[n0 + 2];
      float b3 = binf[n0 + 3] + brecf[n0 + 3];
      #pragma unroll
      for (int nt = 0; nt < 4; ++nt) {
        acc[mt][nt][4 * p + 0] += b0;
        acc[mt][nt][4 * p + 1] += b1;
        acc[mt][nt][4 * p + 2] += b2;
        acc[mt][nt][4 * p + 3] += b3;
        c_pk[mt][nt][2 * p + 0] = pack2bf(acc[mt][nt][4 * p + 0], acc[mt][nt][4 * p + 1]);
        c_pk[mt][nt][2 * p + 1] = pack2bf(acc[mt][nt][4 * p + 2], acc[mt][nt][4 * p + 3]);
      }
    }
  }

  // tanh + swizzled bf16 store of a into LDS.
  // unit u = w*16 + mt*8 + 2p + g stored at byte ((u)^m14)*8 within row; all address
  // pieces except (mt,p) are lane constants -> compiler hoists, zero per-iter VALU.
  auto tanhStore = [&]() {
    #pragma unroll
    for (int mt = 0; mt < 2; ++mt)
      #pragma unroll
      for (int nt = 0; nt < 4; ++nt) {
        #pragma unroll
        for (int p = 0; p < 4; ++p) {
          float t0 = fast_tanh(acc[mt][nt][4 * p + 0]);
          float t1 = fast_tanh(acc[mt][nt][4 * p + 1]);
          float t2 = fast_tanh(acc[mt][nt][4 * p + 2]);
          float t3 = fast_tanh(acc[mt][nt][4 * p + 3]);
          unsigned long long qv =
              (unsigned long long)pack2bf(t0, t1) |
              ((unsigned long long)pack2bf(t2, t3) << 32);
          const int off = rdRow + nt * 32768 + (laneW ^ (mt * 64 + p * 16));
          *(unsigned long long*)(aC + off) = qv;
        }
      }
  };
  tanhStore();
  __syncthreads();

  // ---------- Phase 2: 14 iterations  z^T = Ws @ a^T  (K = 512 -> 32 steps, rotated) ----------
  const uint4* pA = WsP + (w * 2) * 64 + lane;   // + ss*1024 + mt*64

  uint4 Ab[2][2];   // distance-2 rotating prefetch
  #pragma unroll
  for (int d = 0; d < 2; ++d) {
    const int ssd = (d + sOff) & 31;
    #pragma unroll
    for (int mt = 0; mt < 2; ++mt) Ab[d][mt] = pA[ssd * 1024 + mt * 64];
  }

  #pragma unroll 1
  for (int it = 0; it < 14; ++it) {
    // acc <- c (bf16-unpacked; biases already folded in)
    #pragma unroll
    for (int mt = 0; mt < 2; ++mt)
      #pragma unroll
      for (int nt = 0; nt < 4; ++nt)
        #pragma unroll
        for (int p = 0; p < 4; ++p) {
          unsigned int u01 = c_pk[mt][nt][2 * p + 0];
          unsigned int u23 = c_pk[mt][nt][2 * p + 1];
          acc[mt][nt][4 * p + 0] = __builtin_bit_cast(float, u01 << 16);
          acc[mt][nt][4 * p + 1] = __builtin_bit_cast(float, u01 & 0xffff0000u);
          acc[mt][nt][4 * p + 2] = __builtin_bit_cast(float, u23 << 16);
          acc[mt][nt][4 * p + 3] = __builtin_bit_cast(float, u23 & 0xffff0000u);
        }

    #pragma unroll
    for (int s = 0; s < 32; ++s) {
      const int ss = (s + sOff) & 31;
      const int pairB = (ss * 32) ^ vGMb;        // 1 xor (+1 add below) per step
      uint4 B[4];
      #pragma unroll
      for (int nt = 0; nt < 4; ++nt)
        B[nt] = *(const uint4*)(aC + rdRow + nt * 32768 + pairB);  // ds_read_b128
      #pragma unroll
      for (int mt = 0; mt < 2; ++mt)
        #pragma unroll
        for (int nt = 0; nt < 4; ++nt)
          acc[mt][nt] = mfma32(Ab[s & 1][mt], B[nt], acc[mt][nt]);
      if (s + 2 < 32) {
        const int ss2 = (s + 2 + sOff) & 31;
        #pragma unroll
        for (int mt = 0; mt < 2; ++mt)
          Ab[s & 1][mt] = pA[ss2 * 1024 + mt * 64];
      }
    }

    // preload next iteration's first 2 A-steps (hidden by tanh + barriers)
    if (it != 13) {
      #pragma unroll
      for (int d = 0; d < 2; ++d) {
        const int ssd = (d + sOff) & 31;
        #pragma unroll
        for (int mt = 0; mt < 2; ++mt) Ab[d][mt] = pA[ssd * 1024 + mt * 64];
      }
    }

    __syncthreads();   // all reads of old a done
    tanhStore();       // overwrite a in place
    __syncthreads();   // new a visible to all waves
  }

  // ---------- Phase 3: out_proj  y^T = Wout @ a^T (wave w -> channels [w*32, w*32+32)) ----------
  f32x16 o[4];
  #pragma unroll
  for (int nt = 0; nt < 4; ++nt)
    #pragma unroll
    for (int r = 0; r < 16; ++r) o[nt][r] = 0.0f;

  #pragma unroll 2
  for (int s = 0; s < 32; ++s) {
    const int m = w * 32 + il;                  // output-channel row of Wout
    uint4 A = Wout4[m * 64 + 2 * s + g];
    const int pairB = (s * 32) ^ vGMb;
    uint4 B[4];
    #pragma unroll
    for (int nt = 0; nt < 4; ++nt)
      B[nt] = *(const uint4*)(aC + rdRow + nt * 32768 + pairB);
    #pragma unroll
    for (int nt = 0; nt < 4; ++nt)
      o[nt] = mfma32(A, B[nt], o[nt]);
  }
  __syncthreads();   // done reading a; reuse LDS as y staging

  // epilogue: +bout, stage f32 rows into LDS (stride-65 uint4 rows)
  uint4* yst4 = smem4;
  #pragma unroll
  for (int p = 0; p < 4; ++p) {
    const int c0 = w * 32 + 8 * p + 4 * g;
    float b0 = boutf[c0 + 0];
    float b1 = boutf[c0 + 1];
    float b2 = boutf[c0 + 2];
    float b3 = boutf[c0 + 3];
    #pragma unroll
    for (int nt = 0; nt < 4; ++nt) {
      const int irow = nt * 32 + il;
      float4 r;
      r.x = o[nt][4 * p + 0] + b0;
      r.y = o[nt][4 * p + 1] + b1;
      r.z = o[nt][4 * p + 2] + b2;
      r.w = o[nt][4 * p + 3] + b3;
      yst4[irow * 65 + (c0 >> 2)] = __builtin_bit_cast(uint4, r);
    }
  }
  __syncthreads();

  // coalesced f32 store: 8192 uint4 per block, 16 passes x 512 threads
  #pragma unroll
  for (int p = 0; p < 16; ++p) {
    int idx = p * 512 + tid;
    int row = idx >> 6;
    int col = idx & 63;
    y4[(blk * 128 + row) * 64 + col] = yst4[row * 65 + col];
  }
}

extern "C" void kernel_launch(void* const* d_in, const int* in_sizes, int n_in,
                              void* d_out, int out_size, void* d_ws, size_t ws_size,
                              hipStream_t stream) {
  const float* x    = (const float*)d_in[0];
  const float* Win  = (const float*)d_in[1];
  const float* bin  = (const float*)d_in[2];
  const float* W    = (const float*)d_in[3];
  const float* brec = (const float*)d_in[4];
  const float* Wout = (const float*)d_in[5];
  const float* bout = (const float*)d_in[6];

  unsigned short* wsu    = (unsigned short*)d_ws;
  unsigned short* WsP    = wsu;            // 262144 bf16 = 512 KB
  unsigned short* WinBf  = wsu + 262144;   // 131072 bf16 = 256 KB
  unsigned short* WoutBf = wsu + 393216;   // 131072 bf16 = 256 KB

  prep<<<1024, 256, 0, stream>>>(W, Win, Wout, WsP, WinBf, WoutBf);
  attractor_kernel<<<512, 512, 0, stream>>>(x, WinBf, bin, brec, WoutBf, bout,
                                            (const uint4*)WsP, (float*)d_out);
}